// Round 1
// baseline (1128.603 us; speedup 1.0000x reference)
//
#include <hip/hip_runtime.h>

typedef _Float16 half_t;
typedef _Float16 half8 __attribute__((ext_vector_type(8)));
typedef float float4v __attribute__((ext_vector_type(4)));

#define MFMA16(a, b, c) __builtin_amdgcn_mfma_f32_16x16x32_f16(a, b, c, 0, 0, 0)

// ---------------------------------------------------------------------------
// Pack fp32 weights [K][Nw] into MFMA B-fragment order, fp16, zero-padded:
//   out[(((nt*nks + ks)*64 + lane)*8 + j] = W[k][n],
//   n = nt*16 + (lane&15), k = ks*32 + ((lane>>4)<<3) + j
// so a wave's B-frag load for (ntile, kstep) is one coalesced 1KB dwordx4 read.
// ---------------------------------------------------------------------------
__global__ void pack_w(const float* __restrict__ w, half_t* __restrict__ out,
                       int K, int Nw, int nks, int ntiles) {
  int id = blockIdx.x * 256 + threadIdx.x;
  int total = ntiles * nks * 512;
  if (id >= total) return;
  int j = id & 7;
  int lane = (id >> 3) & 63;
  int t3 = id >> 9;
  int ks = t3 % nks;
  int nt = t3 / nks;
  int n = nt * 16 + (lane & 15);
  int k = ks * 32 + ((lane >> 4) << 3) + j;
  float v = (k < K && n < Nw) ? w[k * Nw + n] : 0.0f;
  out[id] = (half_t)v;
}

// ---------------------------------------------------------------------------
// Fused LIIF kernel: 64 queries per WG, 4 waves, N=256 split 4x64 across waves.
// Per corner: chunked gather -> L0 (K=608) -> L1..L3 (K=256, in-place LDS H)
// -> L4 (256->3, K split across waves) -> area-weighted accumulate.
// ---------------------------------------------------------------------------
__global__ __launch_bounds__(256, 2) void liif_main(
    const float* __restrict__ feat, const float* __restrict__ coord,
    const float* __restrict__ cell,
    const half_t* __restrict__ w0p, const half_t* __restrict__ w1p,
    const half_t* __restrict__ w2p, const half_t* __restrict__ w3p,
    const half_t* __restrict__ w4p,
    const float* __restrict__ b0, const float* __restrict__ b1,
    const float* __restrict__ b2, const float* __restrict__ b3,
    const float* __restrict__ b4, float* __restrict__ outp) {
  // LDS ~55 KB total. Strides: Hs 264 halves (132 dw, row starts step 4 banks),
  // Xc 40 halves (20 dw, starts step 20 -> 8 distinct) => 2-way max (free).
  __shared__ alignas(16) half_t Hs[64][264];
  __shared__ alignas(16) half_t Xc[2][64][40];
  __shared__ float S4[4][64][4];
  __shared__ int ix4[4][64];
  __shared__ int iy4[4][64];
  __shared__ float relx4[4][64];
  __shared__ float rely4[4][64];
  __shared__ float area4[4][64];
  __shared__ float cellx[64], celly[64];
  __shared__ float oacc[64][4];
  __shared__ float totv[64];

  const int tid = threadIdx.x;
  const int lane = tid & 63;
  const int wave = tid >> 6;
  const int quad = lane >> 4;
  const int l15 = lane & 15;
  const int blk = blockIdx.x;
  const float* featB = feat + (blk >> 10) * (64 * 128 * 128);  // batch slice

  // ---- per-row, per-corner geometry (t = tid>>6, row = tid&63) ----
  {
    const int t = tid >> 6, row = tid & 63;
    const int gq = blk * 64 + row;
    const float cx0 = coord[gq * 2 + 0], cy0 = coord[gq * 2 + 1];
    const float vx = (t & 2) ? 1.0f : -1.0f;
    const float vy = (t & 1) ? 1.0f : -1.0f;
    const float r = 1.0f / 128.0f, lim = 1.0f - 1e-6f, eps = 1e-6f;
    float cx = fminf(fmaxf(cx0 + vx * r + eps, -lim), lim);
    float cy = fminf(fmaxf(cy0 + vy * r + eps, -lim), lim);
    int ix = (int)floorf((cx + 1.0f) * 64.0f);
    ix = min(max(ix, 0), 127);
    int iy = (int)floorf((cy + 1.0f) * 64.0f);
    iy = min(max(iy, 0), 127);
    float qx = -1.0f + (2.0f * ix + 1.0f) * (1.0f / 128.0f);
    float qy = -1.0f + (2.0f * iy + 1.0f) * (1.0f / 128.0f);
    float rxv = (cx0 - qx) * 128.0f;
    float ryv = (cy0 - qy) * 128.0f;
    ix4[t][row] = ix;
    iy4[t][row] = iy;
    relx4[t][row] = rxv;
    rely4[t][row] = ryv;
    area4[t][row] = fabsf(rxv * ryv) + 1e-9f;
    if (t == 0) {
      cellx[row] = cell[gq * 2 + 0] * 128.0f;
      celly[row] = cell[gq * 2 + 1] * 128.0f;
      oacc[row][0] = 0.0f;
      oacc[row][1] = 0.0f;
      oacc[row][2] = 0.0f;
      totv[row] = 0.0f;
    }
  }
  __syncthreads();

  const float4v zero4 = {0.0f, 0.0f, 0.0f, 0.0f};

#pragma unroll 1
  for (int t = 0; t < 4; t++) {
    // gather one K=32 chunk of X into Xc[buf]: cols [ks*32, ks*32+32)
    auto stage = [&](int ks, int buf) {
#pragma unroll
      for (int e = 0; e < 8; e++) {
        const int idx = e * 256 + tid;
        const int row = idx >> 5;
        const int col = idx & 31;
        const int kk = ks * 32 + col;
        float v = 0.0f;
        if (kk < 576) {
          const int c = kk / 9;
          const int w9 = kk - c * 9;
          const int di = w9 / 3;
          const int dj = w9 - di * 3;
          const int y = ix4[t][row] + di - 1;
          const int x = iy4[t][row] + dj - 1;
          if ((unsigned)y < 128u && (unsigned)x < 128u)
            v = featB[(c << 14) + (y << 7) + x];
        } else if (kk == 576)
          v = relx4[t][row];
        else if (kk == 577)
          v = rely4[t][row];
        else if (kk == 578)
          v = cellx[row];
        else if (kk == 579)
          v = celly[row];
        Xc[buf][row][col] = (half_t)v;
      }
    };

    // ---------------- Layer 0: K = 608 (580 real + pad), 19 k-steps ----------
    float4v acc[4][4];
#pragma unroll
    for (int mt = 0; mt < 4; mt++)
#pragma unroll
      for (int jn = 0; jn < 4; jn++) acc[mt][jn] = zero4;

    half8 bcur[4], bnxt[4];
#pragma unroll
    for (int jn = 0; jn < 4; jn++)
      bcur[jn] = *(const half8*)(w0p + ((((wave * 4 + jn) * 19 + 0) * 64 + lane) << 3));
    stage(0, 0);
    __syncthreads();

#pragma unroll 1
    for (int ks = 0; ks < 19; ks++) {
      const int buf = ks & 1;
      if (ks + 1 < 19) {
        stage(ks + 1, buf ^ 1);
#pragma unroll
        for (int jn = 0; jn < 4; jn++)
          bnxt[jn] =
              *(const half8*)(w0p + ((((wave * 4 + jn) * 19 + ks + 1) * 64 + lane) << 3));
      }
      half8 a[4];
#pragma unroll
      for (int mt = 0; mt < 4; mt++)
        a[mt] = *(const half8*)(&Xc[buf][mt * 16 + l15][quad * 8]);
#pragma unroll
      for (int mt = 0; mt < 4; mt++)
#pragma unroll
        for (int jn = 0; jn < 4; jn++) acc[mt][jn] = MFMA16(a[mt], bcur[jn], acc[mt][jn]);
#pragma unroll
      for (int jn = 0; jn < 4; jn++) bcur[jn] = bnxt[jn];
      __syncthreads();
    }

    // epilogue L0: bias + ReLU -> Hs (fp16)
#pragma unroll
    for (int jn = 0; jn < 4; jn++) {
      const int colg = wave * 64 + jn * 16 + l15;
      const float bb = b0[colg];
#pragma unroll
      for (int mt = 0; mt < 4; mt++)
#pragma unroll
        for (int rr = 0; rr < 4; rr++) {
          float v = acc[mt][jn][rr] + bb;
          Hs[mt * 16 + quad * 4 + rr][colg] = (half_t)fmaxf(v, 0.0f);
        }
    }
    __syncthreads();

    // ---------------- Layers 1..3: K = 256, in-place on Hs -------------------
#pragma unroll 1
    for (int L = 0; L < 3; L++) {
      const half_t* wp = (L == 0) ? w1p : (L == 1) ? w2p : w3p;
      const float* bp = (L == 0) ? b1 : (L == 1) ? b2 : b3;
#pragma unroll
      for (int mt = 0; mt < 4; mt++)
#pragma unroll
        for (int jn = 0; jn < 4; jn++) acc[mt][jn] = zero4;
#pragma unroll
      for (int jn = 0; jn < 4; jn++)
        bcur[jn] = *(const half8*)(wp + ((((wave * 4 + jn) * 8 + 0) * 64 + lane) << 3));
#pragma unroll 1
      for (int ks = 0; ks < 8; ks++) {
        if (ks + 1 < 8) {
#pragma unroll
          for (int jn = 0; jn < 4; jn++)
            bnxt[jn] =
                *(const half8*)(wp + ((((wave * 4 + jn) * 8 + ks + 1) * 64 + lane) << 3));
        }
        half8 a[4];
#pragma unroll
        for (int mt = 0; mt < 4; mt++)
          a[mt] = *(const half8*)(&Hs[mt * 16 + l15][ks * 32 + quad * 8]);
#pragma unroll
        for (int mt = 0; mt < 4; mt++)
#pragma unroll
          for (int jn = 0; jn < 4; jn++)
            acc[mt][jn] = MFMA16(a[mt], bcur[jn], acc[mt][jn]);
#pragma unroll
        for (int jn = 0; jn < 4; jn++) bcur[jn] = bnxt[jn];
      }
      __syncthreads();  // all waves done READING Hs -> safe to overwrite
#pragma unroll
      for (int jn = 0; jn < 4; jn++) {
        const int colg = wave * 64 + jn * 16 + l15;
        const float bb = bp[colg];
#pragma unroll
        for (int mt = 0; mt < 4; mt++)
#pragma unroll
          for (int rr = 0; rr < 4; rr++) {
            float v = acc[mt][jn][rr] + bb;
            Hs[mt * 16 + quad * 4 + rr][colg] = (half_t)fmaxf(v, 0.0f);
          }
      }
      __syncthreads();
    }

    // ---------------- Layer 4: 256 -> 3 (one n-tile, K split across waves) ---
    float4v acc4[4];
#pragma unroll
    for (int mt = 0; mt < 4; mt++) acc4[mt] = zero4;
#pragma unroll
    for (int kx = 0; kx < 2; kx++) {
      const int ks = wave * 2 + kx;
      const half8 bf = *(const half8*)(w4p + ((ks * 64 + lane) << 3));
#pragma unroll
      for (int mt = 0; mt < 4; mt++) {
        half8 a = *(const half8*)(&Hs[mt * 16 + l15][ks * 32 + quad * 8]);
        acc4[mt] = MFMA16(a, bf, acc4[mt]);
      }
    }
    if (l15 < 4) {
#pragma unroll
      for (int mt = 0; mt < 4; mt++)
#pragma unroll
        for (int rr = 0; rr < 4; rr++)
          S4[wave][mt * 16 + quad * 4 + rr][l15] = acc4[mt][rr];
    }
    __syncthreads();

    // reduce partials + area-weighted accumulate (diagonal swap: opp = 3 - t)
    if (tid < 192) {
      const int row = tid / 3;
      const int j = tid - row * 3;
      float pred = b4[j] + S4[0][row][j] + S4[1][row][j] + S4[2][row][j] + S4[3][row][j];
      oacc[row][j] += pred * area4[3 - t][row];
    } else {
      const int row = tid - 192;
      totv[row] += area4[t][row];
    }
    __syncthreads();
  }

  if (tid < 192) {
    const int row = tid / 3;
    const int j = tid - row * 3;
    const int gq = blk * 64 + row;
    outp[gq * 3 + j] = oacc[row][j] / totv[row];
  }
}

// ---------------------------------------------------------------------------
extern "C" void kernel_launch(void* const* d_in, const int* in_sizes, int n_in,
                              void* d_out, int out_size, void* d_ws, size_t ws_size,
                              hipStream_t stream) {
  const float* feat = (const float*)d_in[0];
  const float* coord = (const float*)d_in[1];
  const float* cell = (const float*)d_in[2];
  const float* w0 = (const float*)d_in[3];
  const float* b0 = (const float*)d_in[4];
  const float* w1 = (const float*)d_in[5];
  const float* b1 = (const float*)d_in[6];
  const float* w2 = (const float*)d_in[7];
  const float* b2 = (const float*)d_in[8];
  const float* w3 = (const float*)d_in[9];
  const float* b3 = (const float*)d_in[10];
  const float* w4 = (const float*)d_in[11];
  const float* b4 = (const float*)d_in[12];

  // workspace layout (halves): frag-packed weights, ~713 KB total
  half_t* w0p = (half_t*)d_ws;          // 16 nt * 19 ks * 512 = 155648
  half_t* w1p = w0p + 155648;           // 16 * 8 * 512 = 65536
  half_t* w2p = w1p + 65536;
  half_t* w3p = w2p + 65536;
  half_t* w4p = w3p + 65536;            // 1 * 8 * 512 = 4096

  pack_w<<<608, 256, 0, stream>>>(w0, w0p, 580, 256, 19, 16);
  pack_w<<<256, 256, 0, stream>>>(w1, w1p, 256, 256, 8, 16);
  pack_w<<<256, 256, 0, stream>>>(w2, w2p, 256, 256, 8, 16);
  pack_w<<<256, 256, 0, stream>>>(w3, w3p, 256, 256, 8, 16);
  pack_w<<<16, 256, 0, stream>>>(w4, w4p, 256, 3, 8, 1);

  liif_main<<<2048, 256, 0, stream>>>(feat, coord, cell, w0p, w1p, w2p, w3p, w4p,
                                      b0, b1, b2, b3, b4, (float*)d_out);
}

// Round 2
// 434.109 us; speedup vs baseline: 2.5998x; 2.5998x over previous
//
#include <hip/hip_runtime.h>

typedef _Float16 half_t;
typedef _Float16 half8 __attribute__((ext_vector_type(8)));
typedef float float4v __attribute__((ext_vector_type(4)));

#define MFMA16(a, b, c) __builtin_amdgcn_mfma_f32_16x16x32_f16(a, b, c, 0, 0, 0)

// ---------------------------------------------------------------------------
// Pack fp32 weights [K][Nw] into MFMA B-fragment order, fp16, zero-padded:
//   out[(((nt*nks + ks)*64 + lane)*8 + j] = W[k][n],
//   n = nt*16 + (lane&15), k = ks*32 + ((lane>>4)<<3) + j
// ---------------------------------------------------------------------------
__global__ void pack_w(const float* __restrict__ w, half_t* __restrict__ out,
                       int K, int Nw, int nks, int ntiles) {
  int id = blockIdx.x * 256 + threadIdx.x;
  int total = ntiles * nks * 512;
  if (id >= total) return;
  int j = id & 7;
  int lane = (id >> 3) & 63;
  int t3 = id >> 9;
  int ks = t3 % nks;
  int nt = t3 / nks;
  int n = nt * 16 + (lane & 15);
  int k = ks * 32 + ((lane >> 4) << 3) + j;
  float v = (k < K && n < Nw) ? w[k * Nw + n] : 0.0f;
  out[id] = (half_t)v;
}

// ---------------------------------------------------------------------------
// Z = conv3x3(feat, W0[0:576]) + b0, stored position-major fp16: Z[pos][256].
// 512 blocks: each covers 64 positions (half an image row). M=64,N=256,K=576.
// ---------------------------------------------------------------------------
__global__ __launch_bounds__(256, 2) void conv_l0(
    const float* __restrict__ feat, const half_t* __restrict__ w0p,
    const float* __restrict__ b0, half_t* __restrict__ Z) {
  __shared__ alignas(16) half_t Xc[2][64][40];
  const int tid = threadIdx.x;
  const int lane = tid & 63, wave = tid >> 6, quad = lane >> 4, l15 = lane & 15;
  const int blk = blockIdx.x;
  const int b = blk >> 8;
  const int h = (blk >> 1) & 127;
  const int wbase = (blk & 1) << 6;
  const float* featB = feat + b * (64 * 128 * 128);

  auto stage = [&](int ks, int buf) {
#pragma unroll
    for (int e = 0; e < 8; e++) {
      const int idx = e * 256 + tid;
      const int row = idx >> 5;   // position within tile
      const int col = idx & 31;   // k within chunk
      const int kk = ks * 32 + col;
      const int c = kk / 9;
      const int w9 = kk - c * 9;
      const int di = w9 / 3;
      const int dj = w9 - di * 3;
      const int y = h + di - 1;
      const int x = wbase + row + dj - 1;
      float v = 0.0f;
      if ((unsigned)y < 128u && (unsigned)x < 128u) v = featB[(c << 14) + (y << 7) + x];
      Xc[buf][row][col] = (half_t)v;
    }
  };

  const float4v zero4 = {0.0f, 0.0f, 0.0f, 0.0f};
  float4v acc[4][4];
#pragma unroll
  for (int mt = 0; mt < 4; mt++)
#pragma unroll
    for (int jn = 0; jn < 4; jn++) acc[mt][jn] = zero4;

  half8 bcur[4], bnxt[4];
#pragma unroll
  for (int jn = 0; jn < 4; jn++)
    bcur[jn] = *(const half8*)(w0p + ((((wave * 4 + jn) * 18 + 0) * 64 + lane) << 3));
  stage(0, 0);
  __syncthreads();

#pragma unroll 1
  for (int ks = 0; ks < 18; ks++) {
    const int buf = ks & 1;
    if (ks + 1 < 18) {
      stage(ks + 1, buf ^ 1);
#pragma unroll
      for (int jn = 0; jn < 4; jn++)
        bnxt[jn] =
            *(const half8*)(w0p + ((((wave * 4 + jn) * 18 + ks + 1) * 64 + lane) << 3));
    }
    half8 a[4];
#pragma unroll
    for (int mt = 0; mt < 4; mt++)
      a[mt] = *(const half8*)(&Xc[buf][mt * 16 + l15][quad * 8]);
#pragma unroll
    for (int mt = 0; mt < 4; mt++)
#pragma unroll
      for (int jn = 0; jn < 4; jn++) acc[mt][jn] = MFMA16(a[mt], bcur[jn], acc[mt][jn]);
#pragma unroll
    for (int jn = 0; jn < 4; jn++) bcur[jn] = bnxt[jn];
    __syncthreads();
  }

  const int posbase = b * 16384 + h * 128 + wbase;
#pragma unroll
  for (int jn = 0; jn < 4; jn++) {
    const int colg = wave * 64 + jn * 16 + l15;
    const float bb = b0[colg];
#pragma unroll
    for (int mt = 0; mt < 4; mt++)
#pragma unroll
      for (int rr = 0; rr < 4; rr++) {
        const int row = mt * 16 + quad * 4 + rr;
        Z[(size_t)(posbase + row) * 256 + colg] = (half_t)(acc[mt][jn][rr] + bb);
      }
  }
}

// ---------------------------------------------------------------------------
// Fused LIIF main: 64 queries/WG. Per corner: gather Z rows (contiguous 512B)
// + fp32 rank-4 rel/cell update + ReLU -> Hs; L1..L3 MFMA; L4; ensemble.
// ---------------------------------------------------------------------------
__global__ __launch_bounds__(256, 4) void liif_main(
    const float* __restrict__ coord, const float* __restrict__ cell,
    const half_t* __restrict__ Zp, const float* __restrict__ w0tail,
    const half_t* __restrict__ w1p, const half_t* __restrict__ w2p,
    const half_t* __restrict__ w3p, const half_t* __restrict__ w4p,
    const float* __restrict__ b1, const float* __restrict__ b2,
    const float* __restrict__ b3, const float* __restrict__ b4,
    float* __restrict__ outp) {
  __shared__ alignas(16) half_t Hs[64][264];
  __shared__ int pos4[4][64];
  __shared__ float relx4[4][64], rely4[4][64], area4[4][64];
  __shared__ float cellx[64], celly[64];
  __shared__ float oacc[64][4];
  __shared__ float totv[64];

  const int tid = threadIdx.x;
  const int lane = tid & 63;
  const int wave = tid >> 6;
  const int quad = lane >> 4;
  const int l15 = lane & 15;
  const int blk = blockIdx.x;
  const int batch = blk >> 10;

  // ---- geometry: t = tid>>6 (corner), row = tid&63 (query) ----
  {
    const int t = tid >> 6, row = tid & 63;
    const int gq = blk * 64 + row;
    const float cx0 = coord[gq * 2 + 0], cy0 = coord[gq * 2 + 1];
    const float vx = (t & 2) ? 1.0f : -1.0f;
    const float vy = (t & 1) ? 1.0f : -1.0f;
    const float r = 1.0f / 128.0f, lim = 1.0f - 1e-6f, eps = 1e-6f;
    float cx = fminf(fmaxf(cx0 + vx * r + eps, -lim), lim);
    float cy = fminf(fmaxf(cy0 + vy * r + eps, -lim), lim);
    int ix = (int)floorf((cx + 1.0f) * 64.0f);
    ix = min(max(ix, 0), 127);
    int iy = (int)floorf((cy + 1.0f) * 64.0f);
    iy = min(max(iy, 0), 127);
    float qx = -1.0f + (2.0f * ix + 1.0f) * (1.0f / 128.0f);
    float qy = -1.0f + (2.0f * iy + 1.0f) * (1.0f / 128.0f);
    float rxv = (cx0 - qx) * 128.0f;
    float ryv = (cy0 - qy) * 128.0f;
    pos4[t][row] = (batch << 14) + (ix << 7) + iy;
    relx4[t][row] = rxv;
    rely4[t][row] = ryv;
    area4[t][row] = fabsf(rxv * ryv) + 1e-9f;
    if (t == 0) {
      cellx[row] = cell[gq * 2 + 0] * 128.0f;
      celly[row] = cell[gq * 2 + 1] * 128.0f;
      oacc[row][0] = 0.0f;
      oacc[row][1] = 0.0f;
      oacc[row][2] = 0.0f;
      totv[row] = 0.0f;
    }
  }
  __syncthreads();

  const float4v zero4 = {0.0f, 0.0f, 0.0f, 0.0f};
  const int c8 = tid & 31;           // fixed channel-block (8 channels)
  const int rbase = (tid >> 5) * 8;  // this thread handles rows rbase..rbase+7

#pragma unroll 1
  for (int t = 0; t < 4; t++) {
    // rank-4 weights for this thread's fixed channels (from L2, 8 dwordx4)
    float4v wr[4][2];
#pragma unroll
    for (int r = 0; r < 4; r++) {
      wr[r][0] = *(const float4v*)(w0tail + r * 256 + c8 * 8);
      wr[r][1] = *(const float4v*)(w0tail + r * 256 + c8 * 8 + 4);
    }
    // ---- gather Z + rank-4 + ReLU -> Hs ----
#pragma unroll
    for (int e = 0; e < 8; e++) {
      const int row = rbase + e;
      const int p = pos4[t][row];
      const half8 z = *(const half8*)(Zp + ((size_t)p << 8) + c8 * 8);
      const float rx = relx4[t][row], ry = rely4[t][row];
      const float cx = cellx[row], cy = celly[row];
      half8 hv;
#pragma unroll
      for (int j = 0; j < 8; j++) {
        float v = (float)z[j] + rx * wr[0][j >> 2][j & 3] + ry * wr[1][j >> 2][j & 3] +
                  cx * wr[2][j >> 2][j & 3] + cy * wr[3][j >> 2][j & 3];
        hv[j] = (half_t)fmaxf(v, 0.0f);
      }
      *(half8*)(&Hs[row][c8 * 8]) = hv;
    }
    __syncthreads();

    // ---- layers 1..3: K=256, in-place on Hs ----
    float4v acc[4][4];
    half8 bcur[4], bnxt[4];
#pragma unroll 1
    for (int L = 0; L < 3; L++) {
      const half_t* wp = (L == 0) ? w1p : (L == 1) ? w2p : w3p;
      const float* bp = (L == 0) ? b1 : (L == 1) ? b2 : b3;
#pragma unroll
      for (int mt = 0; mt < 4; mt++)
#pragma unroll
        for (int jn = 0; jn < 4; jn++) acc[mt][jn] = zero4;
#pragma unroll
      for (int jn = 0; jn < 4; jn++)
        bcur[jn] = *(const half8*)(wp + ((((wave * 4 + jn) * 8 + 0) * 64 + lane) << 3));
#pragma unroll 1
      for (int ks = 0; ks < 8; ks++) {
        if (ks + 1 < 8) {
#pragma unroll
          for (int jn = 0; jn < 4; jn++)
            bnxt[jn] =
                *(const half8*)(wp + ((((wave * 4 + jn) * 8 + ks + 1) * 64 + lane) << 3));
        }
        half8 a[4];
#pragma unroll
        for (int mt = 0; mt < 4; mt++)
          a[mt] = *(const half8*)(&Hs[mt * 16 + l15][ks * 32 + quad * 8]);
#pragma unroll
        for (int mt = 0; mt < 4; mt++)
#pragma unroll
          for (int jn = 0; jn < 4; jn++)
            acc[mt][jn] = MFMA16(a[mt], bcur[jn], acc[mt][jn]);
#pragma unroll
        for (int jn = 0; jn < 4; jn++) bcur[jn] = bnxt[jn];
      }
      __syncthreads();  // all waves done READING Hs
#pragma unroll
      for (int jn = 0; jn < 4; jn++) {
        const int colg = wave * 64 + jn * 16 + l15;
        const float bb = bp[colg];
#pragma unroll
        for (int mt = 0; mt < 4; mt++)
#pragma unroll
          for (int rr = 0; rr < 4; rr++) {
            float v = acc[mt][jn][rr] + bb;
            Hs[mt * 16 + quad * 4 + rr][colg] = (half_t)fmaxf(v, 0.0f);
          }
      }
      __syncthreads();
    }

    // ---- layer 4: 256 -> 3, K split across waves ----
    float4v acc4[4];
#pragma unroll
    for (int mt = 0; mt < 4; mt++) acc4[mt] = zero4;
#pragma unroll
    for (int kx = 0; kx < 2; kx++) {
      const int ks = wave * 2 + kx;
      const half8 bf = *(const half8*)(w4p + ((ks * 64 + lane) << 3));
#pragma unroll
      for (int mt = 0; mt < 4; mt++) {
        half8 a = *(const half8*)(&Hs[mt * 16 + l15][ks * 32 + quad * 8]);
        acc4[mt] = MFMA16(a, bf, acc4[mt]);
      }
    }
    __syncthreads();  // all reads of Hs done -> reuse Hs memory for S4
    float* S4f = (float*)&Hs[0][0];
    if (l15 < 4) {
#pragma unroll
      for (int mt = 0; mt < 4; mt++)
#pragma unroll
        for (int rr = 0; rr < 4; rr++)
          S4f[(wave * 64 + mt * 16 + quad * 4 + rr) * 4 + l15] = acc4[mt][rr];
    }
    __syncthreads();

    if (tid < 192) {
      const int row = tid / 3;
      const int j = tid - row * 3;
      float pred = b4[j] + S4f[(0 * 64 + row) * 4 + j] + S4f[(1 * 64 + row) * 4 + j] +
                   S4f[(2 * 64 + row) * 4 + j] + S4f[(3 * 64 + row) * 4 + j];
      oacc[row][j] += pred * area4[3 - t][row];  // diagonal swap
    } else {
      const int row = tid - 192;
      totv[row] += area4[t][row];
    }
    __syncthreads();
  }

  if (tid < 192) {
    const int row = tid / 3;
    const int j = tid - row * 3;
    const int gq = blk * 64 + row;
    outp[gq * 3 + j] = oacc[row][j] / totv[row];
  }
}

// ---------------------------------------------------------------------------
extern "C" void kernel_launch(void* const* d_in, const int* in_sizes, int n_in,
                              void* d_out, int out_size, void* d_ws, size_t ws_size,
                              hipStream_t stream) {
  const float* feat = (const float*)d_in[0];
  const float* coord = (const float*)d_in[1];
  const float* cell = (const float*)d_in[2];
  const float* w0 = (const float*)d_in[3];
  const float* b0 = (const float*)d_in[4];
  const float* w1 = (const float*)d_in[5];
  const float* b1 = (const float*)d_in[6];
  const float* w2 = (const float*)d_in[7];
  const float* b2 = (const float*)d_in[8];
  const float* w3 = (const float*)d_in[9];
  const float* b3 = (const float*)d_in[10];
  const float* w4 = (const float*)d_in[11];
  const float* b4 = (const float*)d_in[12];

  // workspace (halves): packed weights ~680KB, then Z at 1MiB (16MiB fp16)
  half_t* w0p = (half_t*)d_ws;   // 16nt * 18ks * 512 = 147456
  half_t* w1p = w0p + 147456;    // 16 * 8 * 512 = 65536
  half_t* w2p = w1p + 65536;
  half_t* w3p = w2p + 65536;
  half_t* w4p = w3p + 65536;     // 4096
  half_t* Z = (half_t*)d_ws + 524288;  // [2*16384][256] fp16

  pack_w<<<576, 256, 0, stream>>>(w0, w0p, 576, 256, 18, 16);
  pack_w<<<256, 256, 0, stream>>>(w1, w1p, 256, 256, 8, 16);
  pack_w<<<256, 256, 0, stream>>>(w2, w2p, 256, 256, 8, 16);
  pack_w<<<256, 256, 0, stream>>>(w3, w3p, 256, 256, 8, 16);
  pack_w<<<16, 256, 0, stream>>>(w4, w4p, 256, 3, 8, 1);

  conv_l0<<<512, 256, 0, stream>>>(feat, w0p, b0, Z);

  liif_main<<<2048, 256, 0, stream>>>(coord, cell, Z, w0 + 576 * 256, w1p, w2p, w3p,
                                      w4p, b1, b2, b3, b4, (float*)d_out);
}